// Round 2
// baseline (1164.401 us; speedup 1.0000x reference)
//
#include <hip/hip_runtime.h>

// Single-layer GRU, PyTorch semantics, gate order (r,z,n), h0=0.
// T=512, B=1024, I=64, H=64, fp32.
//
// Round 2: LDS-broadcast reads were the bottleneck (384 ds_read_b128/CU/step
// x ~12cyc = 4608 cyc/CU/step, matching measured 993us). This version keeps
// x_t and h_{t-1} distributed across lanes (lane j holds element j) and
// broadcasts via v_readlane_b32 (VALU pipe, SGPR result feeds v_fma_f32's
// scalar operand slot) -- zero LDS traffic in the dot products.
// One barrier per step (double-buffered 4x64-float gate exchange in LDS);
// all 3 waves redundantly compute the gate combine so h stays in-register.

#define T_STEPS 512
#define BATCH   1024
#define IDIM    64
#define HDIM    64

__device__ __forceinline__ float rlane(float v, int k) {
    return __int_as_float(__builtin_amdgcn_readlane(__float_as_int(v), k));
}

__global__ __launch_bounds__(192, 3)
void gru_rl_kernel(const float* __restrict__ X,     // [T,B,I]
                   const float* __restrict__ W_ih,  // [192,64]
                   const float* __restrict__ W_hh,  // [192,64]
                   const float* __restrict__ b_ih,  // [192]
                   const float* __restrict__ b_hh,  // [192]
                   float* __restrict__ out)         // [T*B*H] ++ [B*H]
{
    const int tid  = threadIdx.x;
    const int g    = tid >> 6;       // 0:r 1:z 2:n
    const int j    = tid & 63;       // hidden unit (= lane)
    const int gr   = g * 64 + j;     // gate row in [0,192)
    const int brow = blockIdx.x;     // batch row

    // double-buffered gate-preactivation exchange (tiny; 2KB)
    __shared__ float sR[2][64], sZ[2][64], sNX[2][64], sNH[2][64];

    // ---- weight rows in registers (static indices only) ----
    float w[128];
    {
        const float4* wi = (const float4*)(W_ih + gr * 64);
        const float4* wh = (const float4*)(W_hh + gr * 64);
        #pragma unroll
        for (int k = 0; k < 16; ++k) {
            float4 a = wi[k];
            w[4*k+0] = a.x; w[4*k+1] = a.y; w[4*k+2] = a.z; w[4*k+3] = a.w;
        }
        #pragma unroll
        for (int k = 0; k < 16; ++k) {
            float4 a = wh[k];
            w[64+4*k+0] = a.x; w[64+4*k+1] = a.y; w[64+4*k+2] = a.z; w[64+4*k+3] = a.w;
        }
    }
    const float bi = b_ih[gr];
    const float bh = b_hh[gr];

    float hv = 0.0f;                          // lane j holds h[j]
    float xv = X[brow * IDIM + j];            // lane j holds x_t[j]
    float xvn = 0.0f;

    for (int t = 0; t < T_STEPS; ++t) {
        // prefetch next x (covered by ~600 cyc of dot-product VALU below)
        if (t + 1 < T_STEPS)
            xvn = X[((t + 1) * BATCH + brow) * IDIM + j];

        // ---- dots via readlane broadcast; 2 accumulators per side ----
        float a0 = (g == 2) ? bi : (bi + bh);   // x-side (+ merged bias)
        float a1 = 0.0f;
        float c0 = (g == 2) ? bh : 0.0f;        // h-side
        float c1 = 0.0f;
        #pragma unroll
        for (int k = 0; k < 64; k += 2) {
            a0 = fmaf(rlane(xv, k),     w[k],     a0);
            a1 = fmaf(rlane(xv, k + 1), w[k + 1], a1);
        }
        #pragma unroll
        for (int k = 0; k < 64; k += 2) {
            c0 = fmaf(rlane(hv, k),     w[64 + k],     c0);
            c1 = fmaf(rlane(hv, k + 1), w[64 + k + 1], c1);
        }
        const float aS = a0 + a1;
        const float cS = c0 + c1;

        const int p = t & 1;
        if (g == 0)      { sR[p][j] = aS + cS; }
        else if (g == 1) { sZ[p][j] = aS + cS; }
        else             { sNX[p][j] = aS; sNH[p][j] = cS; }
        __syncthreads();   // single barrier per step (exchange is dbuf'd)

        // ---- gate combine, done redundantly by all 3 waves ----
        const float r    = 1.0f / (1.0f + __expf(-sR[p][j]));
        const float z    = 1.0f / (1.0f + __expf(-sZ[p][j]));
        const float npre = sNX[p][j] + r * sNH[p][j];
        const float e    = __expf(2.0f * npre);        // tanh, inf-safe
        const float n    = 1.0f - 2.0f / (e + 1.0f);
        const float hn   = fmaf(z, hv - n, n);         // (1-z)n + z*h
        hv = hn;

        if (g == 0)
            out[(t * BATCH + brow) * HDIM + j] = hn;
        xv = xvn;
    }

    if (g == 0)
        out[T_STEPS * BATCH * HDIM + brow * HDIM + j] = hv;  // h_last
}

extern "C" void kernel_launch(void* const* d_in, const int* in_sizes, int n_in,
                              void* d_out, int out_size, void* d_ws, size_t ws_size,
                              hipStream_t stream) {
    const float* X    = (const float*)d_in[0];
    const float* W_ih = (const float*)d_in[1];
    const float* W_hh = (const float*)d_in[2];
    const float* b_ih = (const float*)d_in[3];
    const float* b_hh = (const float*)d_in[4];
    float* out = (float*)d_out;

    dim3 grid(BATCH);
    dim3 block(192);
    gru_rl_kernel<<<grid, block, 0, stream>>>(X, W_ih, W_hh, b_ih, b_hh, out);
}

// Round 3
// 344.459 us; speedup vs baseline: 3.3804x; 3.3804x over previous
//
#include <hip/hip_runtime.h>

// GRU via fp16 MFMA, fp32 accumulate. T=512, B=1024, I=H=64.
// 64 blocks x 256 threads (4 waves). Block owns 16 batch rows; wave w owns
// hidden units [16w,16w+16). Per step each wave: 12x mfma_f32_16x16x32_f16
// (r,z with K=128 = [x|h] concat; nx,nh with K=64), gate combine per-lane in
// C-layout, h kept in C-layout regs + round-tripped through a tiny
// double-buffered LDS tile (fp16, stride 72 -> 2-way-only bank aliasing) to
// rebuild A-fragments. One raw s_barrier + lgkmcnt(0) per step (NO
// __syncthreads -> the 2-step-deep X prefetch stays in flight across the
// barrier). C-layout (verified): col=lane&15, row=(lane>>4)*4+reg.
// A/B k-mapping: k = 8*(lane>>4)+e on both sides (any consistent bijection
// cancels), rows/cols on lane&15.

typedef _Float16 half8 __attribute__((ext_vector_type(8)));
typedef float    f32x4 __attribute__((ext_vector_type(4)));

#define T_STEPS 512
#define BATCH   1024

struct XBuf { float4 a0, a1, b0, b1; };

__device__ __forceinline__ half8 cvt8(const float4& a, const float4& b) {
    half8 h;
    h[0] = (_Float16)a.x; h[1] = (_Float16)a.y; h[2] = (_Float16)a.z; h[3] = (_Float16)a.w;
    h[4] = (_Float16)b.x; h[5] = (_Float16)b.y; h[6] = (_Float16)b.z; h[7] = (_Float16)b.w;
    return h;
}

__device__ __forceinline__ half8 loadw8(const float* p) {
    const float4* q = (const float4*)p;
    float4 a = q[0], b = q[1];
    return cvt8(a, b);
}

__device__ __forceinline__ void block_sync() {
    asm volatile("s_waitcnt lgkmcnt(0)" ::: "memory");
    __builtin_amdgcn_s_barrier();
    asm volatile("" ::: "memory");
}

#define MFMA16(A, B, C) __builtin_amdgcn_mfma_f32_16x16x32_f16((A), (B), (C), 0, 0, 0)

__global__ __launch_bounds__(256, 1)
void gru_mfma_kernel(const float* __restrict__ X,     // [T,B,64]
                     const float* __restrict__ W_ih,  // [192,64]
                     const float* __restrict__ W_hh,  // [192,64]
                     const float* __restrict__ b_ih,  // [192]
                     const float* __restrict__ b_hh,  // [192]
                     float* __restrict__ out)         // [T*B*64] ++ [B*64]
{
    const int tid   = threadIdx.x;
    const int w     = tid >> 6;        // wave: units [16w,16w+16)
    const int l     = tid & 63;
    const int c     = l & 15;          // A-row / B-col / C-col
    const int g4    = l >> 4;          // lane group (k-slot / C-row group)
    const int u     = w * 16 + c;      // this lane's hidden-unit column
    const int row   = c;               // A-fragment row (batch row within tile)
    const int brow0 = blockIdx.x * 16;

    __shared__ __align__(16) _Float16 hbuf[2][16][72];  // stride 72: 2-way only

    // ---- B-fragments (W columns), fp16, once ----
    // r/z: K=128 concat [W_ih row | W_hh row]; frag f covers k in [32f,32f+32),
    // lane slice k = 32f + 8*g4 + e.
    const half8 Br0 = loadw8(W_ih + (u)       * 64 +  0 + 8 * g4);
    const half8 Br1 = loadw8(W_ih + (u)       * 64 + 32 + 8 * g4);
    const half8 Br2 = loadw8(W_hh + (u)       * 64 +  0 + 8 * g4);
    const half8 Br3 = loadw8(W_hh + (u)       * 64 + 32 + 8 * g4);
    const half8 Bz0 = loadw8(W_ih + (64 + u)  * 64 +  0 + 8 * g4);
    const half8 Bz1 = loadw8(W_ih + (64 + u)  * 64 + 32 + 8 * g4);
    const half8 Bz2 = loadw8(W_hh + (64 + u)  * 64 +  0 + 8 * g4);
    const half8 Bz3 = loadw8(W_hh + (64 + u)  * 64 + 32 + 8 * g4);
    const half8 Bnx0 = loadw8(W_ih + (128 + u) * 64 +  0 + 8 * g4);
    const half8 Bnx1 = loadw8(W_ih + (128 + u) * 64 + 32 + 8 * g4);
    const half8 Bnh0 = loadw8(W_hh + (128 + u) * 64 +  0 + 8 * g4);
    const half8 Bnh1 = loadw8(W_hh + (128 + u) * 64 + 32 + 8 * g4);

    const float rb  = b_ih[u]        + b_hh[u];
    const float zb  = b_ih[64 + u]   + b_hh[64 + u];
    const float nxb = b_ih[128 + u];
    const float nhb = b_hh[128 + u];

    f32x4 hp = {0.f, 0.f, 0.f, 0.f};   // h in C-layout: row 4*g4+i, col u

#define ISSUE_X(XB, T) do {                                                   \
        const float* px_ = X + ((T) * BATCH + brow0 + row) * 64 + 8 * g4;     \
        (XB).a0 = ((const float4*)px_)[0];                                    \
        (XB).a1 = ((const float4*)px_)[1];                                    \
        const float* py_ = px_ + 32;                                          \
        (XB).b0 = ((const float4*)py_)[0];                                    \
        (XB).b1 = ((const float4*)py_)[1];                                    \
    } while (0)

    XBuf xb0, xb1;
    ISSUE_X(xb0, 0);
    ISSUE_X(xb1, 1);

    // zero h(t=0) buffer
    for (int k = tid; k < 16 * 72; k += 256)
        ((_Float16*)hbuf)[k] = (_Float16)0.f;
    __syncthreads();

#define STEP(T, XB) do {                                                      \
        const int p_ = (T) & 1;                                               \
        const half8 hf0 = *(const half8*)&hbuf[p_][row][8 * g4];              \
        const half8 hf1 = *(const half8*)&hbuf[p_][row][32 + 8 * g4];         \
        const half8 xf0 = cvt8((XB).a0, (XB).a1);                             \
        const half8 xf1 = cvt8((XB).b0, (XB).b1);                             \
        { int tn_ = (T) + 2; if (tn_ > T_STEPS - 1) tn_ = T_STEPS - 1;        \
          ISSUE_X(XB, tn_); }                                                 \
        f32x4 cr  = {rb, rb, rb, rb};                                         \
        f32x4 cz  = {zb, zb, zb, zb};                                         \
        f32x4 cnx = {nxb, nxb, nxb, nxb};                                     \
        f32x4 cnh = {nhb, nhb, nhb, nhb};                                     \
        cr  = MFMA16(xf0, Br0, cr);   cr  = MFMA16(xf1, Br1, cr);             \
        cz  = MFMA16(xf0, Bz0, cz);   cz  = MFMA16(xf1, Bz1, cz);             \
        cnx = MFMA16(xf0, Bnx0, cnx); cnx = MFMA16(xf1, Bnx1, cnx);           \
        cr  = MFMA16(hf0, Br2, cr);   cr  = MFMA16(hf1, Br3, cr);             \
        cz  = MFMA16(hf0, Bz2, cz);   cz  = MFMA16(hf1, Bz3, cz);             \
        cnh = MFMA16(hf0, Bnh0, cnh); cnh = MFMA16(hf1, Bnh1, cnh);           \
        _Pragma("unroll")                                                     \
        for (int i = 0; i < 4; ++i) {                                         \
            const float rv = __builtin_amdgcn_rcpf(1.f + __expf(-cr[i]));     \
            const float zv = __builtin_amdgcn_rcpf(1.f + __expf(-cz[i]));     \
            const float npre = fmaf(rv, cnh[i], cnx[i]);                      \
            const float nv =                                                  \
                1.f - 2.f * __builtin_amdgcn_rcpf(1.f + __expf(2.f * npre));  \
            const float hn = fmaf(zv, hp[i] - nv, nv);                        \
            hp[i] = hn;                                                       \
            hbuf[p_ ^ 1][4 * g4 + i][u] = (_Float16)hn;                       \
            out[((T) * BATCH + brow0 + 4 * g4 + i) * 64 + u] = hn;            \
        }                                                                     \
        block_sync();                                                         \
    } while (0)

    #pragma unroll 1
    for (int t = 0; t < T_STEPS; t += 2) {
        STEP(t, xb0);
        STEP(t + 1, xb1);
    }

    #pragma unroll
    for (int i = 0; i < 4; ++i)
        out[T_STEPS * BATCH * 64 + (brow0 + 4 * g4 + i) * 64 + u] = hp[i];

#undef STEP
#undef ISSUE_X
}

extern "C" void kernel_launch(void* const* d_in, const int* in_sizes, int n_in,
                              void* d_out, int out_size, void* d_ws, size_t ws_size,
                              hipStream_t stream) {
    const float* X    = (const float*)d_in[0];
    const float* W_ih = (const float*)d_in[1];
    const float* W_hh = (const float*)d_in[2];
    const float* b_ih = (const float*)d_in[3];
    const float* b_hh = (const float*)d_in[4];
    float* out = (float*)d_out;

    dim3 grid(BATCH / 16);   // 64 blocks
    dim3 block(256);         // 4 waves
    gru_mfma_kernel<<<grid, block, 0, stream>>>(X, W_ih, W_hh, b_ih, b_hh, out);
}